// Round 3
// baseline (279.843 us; speedup 1.0000x reference)
//
#include <hip/hip_runtime.h>

// OTAM cumulative-distance matching, fused forward+transposed DP, one pass.
// similarity: [2048, 128, 16, 16] f32 ; out: [2048, 128] f32
//
// v3: coalesced global->LDS staging per wave (8 full 128B lines per load
// instruction instead of 64 scattered 16B requests), wave-private LDS
// (no barriers), register-prefetch pipeline, swizzled conflict-free LDS.

#define K2   14.4269504088896340736f   // 1/(lambda*ln2), lambda = 0.1
#define LL2  0.069314718055994530942f  // lambda*ln(2)

// softmin(a,b) = -L*ln(e^{-a/L} + e^{-b/L}) = min - L*ln2*log2(1 + exp2(-|a-b|/(L*ln2)))
__device__ __forceinline__ float softmin2(float a, float b) {
    float mn = fminf(a, b);
    float t  = __builtin_amdgcn_exp2f(-K2 * fabsf(a - b));
    return mn - LL2 * __builtin_amdgcn_logf(1.0f + t);   // logf = v_log_f32 = log2
}

__device__ __forceinline__ float softmin3(float a, float b, float c) {
    float mn = fminf(fminf(a, b), c);   // v_min3_f32
    float s = __builtin_amdgcn_exp2f(-K2 * (a - mn))
            + __builtin_amdgcn_exp2f(-K2 * (b - mn))
            + __builtin_amdgcn_exp2f(-K2 * (c - mn));
    return mn - LL2 * __builtin_amdgcn_logf(s);
}

// DP1 (row-major over D): one row step, in-place with diagonal carry.
__device__ __forceinline__ void dp_row(float* R, const float* dr) {
    float diag = R[0];              // cum1[r-1, 0] = 0
    float oldR = R[1];
    R[1] = dr[0] + softmin3(diag, R[0], oldR);   // m = 1 boundary
    diag = oldR;
#pragma unroll
    for (int m = 2; m <= 16; ++m) {
        float o = R[m];
        R[m] = dr[m - 1] + softmin2(diag, R[m - 1]);
        diag = o;
    }
    R[17] = softmin3(diag, R[16], R[17]);        // m = 17 pad, d = 0, boundary
}

// DP2 (the DP on D^T, advanced column-major): one interior column step.
__device__ __forceinline__ void dp_col(float* C, const float* dr) {
    float diag2 = C[0];             // cum2[0, m-1]
    C[0] = C[0] + dr[0];            // row 0 of DP2 is a plain cumsum
#pragma unroll
    for (int l = 1; l < 16; ++l) {
        float o = C[l];
        C[l] = dr[l] + softmin2(diag2, o);
        diag2 = o;
    }
}

// LDS layout per wave-chunk (2 rows x 64 pairs = 2048 floats):
//   float j (0..31) of pair p lives at  (j>>2)*256 + (j&3)*64 + ((p + 8*(j>>2)) & 63)
// Writes (fixed c): bank = (p + 8b) % 32, b = lane&7 -> every bank hit exactly 2x: free.
// Reads  (fixed g,c): bank = (t + 8g) % 32 -> 2x per bank: free.
__device__ __forceinline__ void write_chunk(float* lds, const float4* pf, int t) {
    const int a = t >> 3, b = t & 7;
#pragma unroll
    for (int i = 0; i < 8; ++i) {
        int p = i * 8 + a;
        int base = b * 256 + ((p + 8 * b) & 63);
        lds[base]       = 1.0f - pf[i].x;
        lds[base + 64]  = 1.0f - pf[i].y;
        lds[base + 128] = 1.0f - pf[i].z;
        lds[base + 192] = 1.0f - pf[i].w;
    }
}

__device__ __forceinline__ void read_row(const float* lds, int rr, int t, float* dr) {
#pragma unroll
    for (int g4 = 0; g4 < 4; ++g4) {
        int g = rr * 4 + g4;
        int base = g * 256 + ((t + 8 * g) & 63);
        dr[g4 * 4 + 0] = lds[base];
        dr[g4 * 4 + 1] = lds[base + 64];
        dr[g4 * 4 + 2] = lds[base + 128];
        dr[g4 * 4 + 3] = lds[base + 192];
    }
}

__global__ __launch_bounds__(256, 4)
void otam_fused_kernel(const float* __restrict__ sim, float* __restrict__ out) {
    const int t     = threadIdx.x & 63;
    const int wv    = threadIdx.x >> 6;
    const int pair0 = blockIdx.x * 256 + wv * 64;    // first pair of this wave

    __shared__ float lds_all[8192];                  // 32 KB: 4 waves x 2048 floats
    float* lds = lds_all + (wv << 11);               // wave-private -> no barriers

    // staging source: lane t' loads float4 #(t&7) of pair pair0+(t>>3), +i*8 pairs
    const float* sbase = sim + (((size_t)(pair0 + (t >> 3))) << 8) + ((t & 7) << 2);

    float R[18];   // DP1 row state
    float C[16];   // DP2 column state
    float dr[16];
    float4 pf[8];  // prefetch registers

    // ---- prologue: load chunk 0 (rows 0,1) ----
#pragma unroll
    for (int i = 0; i < 8; ++i)
        pf[i] = *reinterpret_cast<const float4*>(sbase + i * 2048);

    write_chunk(lds, pf, t);
#pragma unroll
    for (int i = 0; i < 8; ++i)      // prefetch chunk 1
        pf[i] = *reinterpret_cast<const float4*>(sbase + i * 2048 + 32);

    // ---- row 0: DP1 row 0 = cumsum; DP2 column m=1 (boundary) ----
    read_row(lds, 0, t, dr);
    R[0] = 0.0f;
#pragma unroll
    for (int m = 1; m <= 16; ++m) R[m] = R[m - 1] + dr[m - 1];
    R[17] = R[16];
    C[0] = dr[0];
#pragma unroll
    for (int l = 1; l < 16; ++l)
        C[l] = dr[l] + softmin3(0.0f, 0.0f, C[l - 1]);

    // ---- row 1 ----
    read_row(lds, 1, t, dr);
    dp_row(R, dr);
    dp_col(C, dr);

    // ---- chunks 1..7 (rows 2..15), register-prefetch pipeline ----
#pragma unroll
    for (int rc = 1; rc < 8; ++rc) {
        write_chunk(lds, pf, t);                     // waits vmcnt internally
        if (rc < 7) {
#pragma unroll
            for (int i = 0; i < 8; ++i)              // prefetch chunk rc+1
                pf[i] = *reinterpret_cast<const float4*>(sbase + i * 2048 + (rc + 1) * 32);
        }
        read_row(lds, 0, t, dr);
        dp_row(R, dr);
        dp_col(C, dr);
        read_row(lds, 1, t, dr);
        dp_row(R, dr);
        dp_col(C, dr);
    }

    // ---- DP2 final column m = 17: d = 0, boundary ----
    {
        float diag2 = C[0];
#pragma unroll
        for (int l = 1; l < 16; ++l) {
            float o = C[l];
            C[l] = softmin3(diag2, o, C[l - 1]);
            diag2 = o;
        }
    }

    out[pair0 + t] = -0.5f * (R[17] + C[15]);
}

extern "C" void kernel_launch(void* const* d_in, const int* in_sizes, int n_in,
                              void* d_out, int out_size, void* d_ws, size_t ws_size,
                              hipStream_t stream) {
    const float* sim = (const float*)d_in[0];
    float* out = (float*)d_out;
    int npairs = in_sizes[0] >> 8;          // (Q*S*16*16)/256 = 262144
    int grid = npairs >> 8;                 // 256 pairs per block (assumes %256==0)
    otam_fused_kernel<<<grid, 256, 0, stream>>>(sim, out);
}

// Round 4
// 54.585 us; speedup vs baseline: 5.1268x; 5.1268x over previous
//
#include <hip/hip_runtime.h>

// OTAM cumulative-distance matching, fused forward+transposed DP, one pass.
// similarity: [2048, 128, 16, 16] f32 ; out: [2048, 128] f32
//
// v4: coalesced global loads (8 full 128B lines per instr) -> conflict-free
// XOR-swizzled LDS (b128 writes+reads only) -> per-thread fused DP.
// Wave-private LDS quadrant => no barriers. No register prefetch pipeline
// (TLP covers latency); launch_bounds(256,2) so nothing spills.

#define K2   14.4269504088896340736f   // 1/(lambda*ln2), lambda = 0.1
#define LL2  0.069314718055994530942f  // lambda*ln(2)

// softmin(a,b) = min - L*ln2*log2(1 + exp2(-|a-b|/(L*ln2)))
__device__ __forceinline__ float softmin2(float a, float b) {
    float mn = fminf(a, b);
    float t  = __builtin_amdgcn_exp2f(-K2 * fabsf(a - b));
    return mn - LL2 * __builtin_amdgcn_logf(1.0f + t);   // logf = v_log_f32 = log2
}

__device__ __forceinline__ float softmin3(float a, float b, float c) {
    float mn = fminf(fminf(a, b), c);   // v_min3_f32
    float s = __builtin_amdgcn_exp2f(-K2 * (a - mn))
            + __builtin_amdgcn_exp2f(-K2 * (b - mn))
            + __builtin_amdgcn_exp2f(-K2 * (c - mn));
    return mn - LL2 * __builtin_amdgcn_logf(s);
}

// DP1 (row-major over D): one row step, in-place with diagonal carry.
__device__ __forceinline__ void dp_row(float* R, const float* dr) {
    float diag = R[0];              // cum1[r-1, 0] = 0
    float oldR = R[1];
    R[1] = dr[0] + softmin3(diag, R[0], oldR);   // m = 1 boundary
    diag = oldR;
#pragma unroll
    for (int m = 2; m <= 16; ++m) {
        float o = R[m];
        R[m] = dr[m - 1] + softmin2(diag, R[m - 1]);
        diag = o;
    }
    R[17] = softmin3(diag, R[16], R[17]);        // m = 17 pad, d = 0, boundary
}

// DP2 (the DP on D^T, advanced column-major): one interior column step.
__device__ __forceinline__ void dp_col(float* C, const float* dr) {
    float diag2 = C[0];             // cum2[0, m-1]
    C[0] = C[0] + dr[0];            // row 0 of DP2 is a plain cumsum
#pragma unroll
    for (int l = 1; l < 16; ++l) {
        float o = C[l];
        C[l] = dr[l] + softmin2(diag2, o);
        diag2 = o;
    }
}

// LDS layout per wave (single 8 KB buffer, one 2-row chunk of 64 pairs):
// float4 #f (f=0..7) of pair p's 128B block lives at float4-slot p*8 + (f^(p&7)).
// Writes: instr i, lane t holds f=(t&7) of p=i*8+(t>>3) -> slot i*64+(t>>3)*8+((t&7)^(t>>3)).
// Reads:  lane t, float4 k of sub-row rr -> slot t*8 + ((rr*4+k)^(t&7)).
// Both: every 8 consecutive lanes cover all 32 banks exactly once (b128-conflict-free).

__global__ __launch_bounds__(256, 2)
void otam_fused_kernel(const float* __restrict__ sim, float* __restrict__ out) {
    const int t  = threadIdx.x & 63;
    const int wv = threadIdx.x >> 6;
    const int pair0 = blockIdx.x * 256 + wv * 64;

    __shared__ float lds_all[4 * 2048];              // 32 KB total
    float* lds = lds_all + (wv << 11);               // wave-private 8 KB

    const int u = t >> 3;                            // 0..7
    const int c = t & 7;                             // 0..7

    // global: instr i of chunk rc -> pair (pair0 + i*8 + u), bytes rc*128 + c*16
    const float* gbase = sim + (((size_t)(pair0 + u)) << 8) + (c << 2);
    // LDS write base (floats): slot (u*8 + (c^u)) ; + i*256 floats per instr
    float* wbase = lds + ((u * 8 + (c ^ u)) << 2);

    float R[18], C[16], dr[16];

    // ---------- chunk 0 (rows 0,1) ----------
    {
        float4 ld[8];
#pragma unroll
        for (int i = 0; i < 8; ++i)
            ld[i] = *reinterpret_cast<const float4*>(gbase + i * 2048);
#pragma unroll
        for (int i = 0; i < 8; ++i) {
            float4 w;
            w.x = 1.0f - ld[i].x; w.y = 1.0f - ld[i].y;
            w.z = 1.0f - ld[i].z; w.w = 1.0f - ld[i].w;
            *reinterpret_cast<float4*>(wbase + i * 256) = w;
        }
    }

    // row 0: DP1 row 0 = cumsum; DP2 column m=1 (boundary)
#pragma unroll
    for (int k = 0; k < 4; ++k) {
        float4 v = *reinterpret_cast<const float4*>(lds + t * 32 + ((k ^ c) << 2));
        dr[k * 4 + 0] = v.x; dr[k * 4 + 1] = v.y; dr[k * 4 + 2] = v.z; dr[k * 4 + 3] = v.w;
    }
    R[0] = 0.0f;
#pragma unroll
    for (int m = 1; m <= 16; ++m) R[m] = R[m - 1] + dr[m - 1];
    R[17] = R[16];
    C[0] = dr[0];
#pragma unroll
    for (int l = 1; l < 16; ++l)
        C[l] = dr[l] + softmin3(0.0f, 0.0f, C[l - 1]);

    // row 1
#pragma unroll
    for (int k = 0; k < 4; ++k) {
        float4 v = *reinterpret_cast<const float4*>(lds + t * 32 + (((4 + k) ^ c) << 2));
        dr[k * 4 + 0] = v.x; dr[k * 4 + 1] = v.y; dr[k * 4 + 2] = v.z; dr[k * 4 + 3] = v.w;
    }
    dp_row(R, dr);
    dp_col(C, dr);

    // ---------- chunks 1..7 (rows 2..15) ----------
    for (int rc = 1; rc < 8; ++rc) {
        {
            float4 ld[8];
#pragma unroll
            for (int i = 0; i < 8; ++i)
                ld[i] = *reinterpret_cast<const float4*>(gbase + i * 2048 + rc * 32);
#pragma unroll
            for (int i = 0; i < 8; ++i) {
                float4 w;
                w.x = 1.0f - ld[i].x; w.y = 1.0f - ld[i].y;
                w.z = 1.0f - ld[i].z; w.w = 1.0f - ld[i].w;
                *reinterpret_cast<float4*>(wbase + i * 256) = w;
            }
        }
#pragma unroll
        for (int rr = 0; rr < 2; ++rr) {
#pragma unroll
            for (int k = 0; k < 4; ++k) {
                float4 v = *reinterpret_cast<const float4*>(lds + t * 32 + (((rr * 4 + k) ^ c) << 2));
                dr[k * 4 + 0] = v.x; dr[k * 4 + 1] = v.y; dr[k * 4 + 2] = v.z; dr[k * 4 + 3] = v.w;
            }
            dp_row(R, dr);
            dp_col(C, dr);
        }
    }

    // ---------- DP2 final column m = 17 (d = 0, boundary) ----------
    {
        float diag2 = C[0];
#pragma unroll
        for (int l = 1; l < 16; ++l) {
            float o = C[l];
            C[l] = softmin3(diag2, o, C[l - 1]);
            diag2 = o;
        }
    }

    out[pair0 + t] = -0.5f * (R[17] + C[15]);
}

extern "C" void kernel_launch(void* const* d_in, const int* in_sizes, int n_in,
                              void* d_out, int out_size, void* d_ws, size_t ws_size,
                              hipStream_t stream) {
    const float* sim = (const float*)d_in[0];
    float* out = (float*)d_out;
    int npairs = in_sizes[0] >> 8;          // 262144
    int grid = npairs >> 8;                 // 256 pairs per block
    otam_fused_kernel<<<grid, 256, 0, stream>>>(sim, out);
}